// Round 2
// baseline (8704.672 us; speedup 1.0000x reference)
//
#include <hip/hip_runtime.h>
#include <stdint.h>

// Problem dims (fixed by setup_inputs)
#define BB 8
#define SS 2048
#define DD 1024
#define HH 4096
#define MM 256

typedef short bf16x8 __attribute__((ext_vector_type(8)));   // 8 bf16 in 4 VGPRs
typedef float f32x4 __attribute__((ext_vector_type(4)));

__device__ inline unsigned short f2bf(float f){
  unsigned u = __builtin_bit_cast(unsigned, f);
  return (unsigned short)((u + 0x7FFFu + ((u >> 16) & 1u)) >> 16);  // RNE
}

// ---------------- pack f32 -> bf16 (4 elems/thread) ----------------
__global__ void ssma_pack_bf16(const float* __restrict__ src,
                               unsigned short* __restrict__ dst, int n4){
  int i = blockIdx.x * blockDim.x + threadIdx.x;
  if (i < n4){
    float4 v = ((const float4*)src)[i];
    ushort4 o;
    o.x = f2bf(v.x); o.y = f2bf(v.y); o.z = f2bf(v.z); o.w = f2bf(v.w);
    ((ushort4*)dst)[i] = o;
  }
}

// ---------------- bf16 MFMA GEMM, C = A * B^T (+epilogue) ----------------
// A: (M,K) bf16 row-major.  Bw: (N,K) bf16 row-major (so rows are B^T cols).
// EPI==0: C(bf16) = relu(acc + bias[n])          (GEMM1 -> h)
// EPI==1: C(f32)  = acc + resid[m,n] + bias[n]   (GEMM2 -> out)
template<int EPI>
__global__ __launch_bounds__(256) void ssma_gemm_bt(
    const unsigned short* __restrict__ A, const unsigned short* __restrict__ Bw,
    int K, int N, const float* __restrict__ bias,
    const float* __restrict__ resid, void* __restrict__ Cout)
{
  // 128x32 bf16 tile = 4096 bf16 = 512 uint4 = 8KB each  (round-1 fix: was [256] -> OOB)
  __shared__ uint4 As4[512];
  __shared__ uint4 Bs4[512];
  unsigned short* As = (unsigned short*)As4;
  unsigned short* Bs = (unsigned short*)Bs4;

  const int tid  = threadIdx.x;
  const int lane = tid & 63;
  const int wv   = tid >> 6;
  const int wm   = wv >> 1, wn = wv & 1;      // 2x2 wave grid, 64x64 per wave
  const int m0   = blockIdx.y * 128;
  const int n0   = blockIdx.x * 128;
  const int kq   = lane >> 4;                 // 0..3 (k-subblock of 8)
  const int rl   = lane & 15;                 // row within 16

  f32x4 acc[4][4];
#pragma unroll
  for (int a = 0; a < 4; ++a)
#pragma unroll
    for (int b = 0; b < 4; ++b) acc[a][b] = (f32x4){0.f, 0.f, 0.f, 0.f};

  for (int k0 = 0; k0 < K; k0 += 32){
    __syncthreads();
    // stage 128x32 A-tile and B-tile (16B per chunk, 2 chunks/thread each)
#pragma unroll
    for (int i = 0; i < 2; ++i){
      int c  = tid + 256 * i;          // 0..511
      int r  = c >> 2;                 // row 0..127
      int c8 = (c & 3) * 8;            // col start
      As4[c] = *(const uint4*)(A  + (size_t)(m0 + r) * K + k0 + c8);
      Bs4[c] = *(const uint4*)(Bw + (size_t)(n0 + r) * K + k0 + c8);
    }
    __syncthreads();

    const bf16x8* Ap = (const bf16x8*)As;
    const bf16x8* Bp = (const bf16x8*)Bs;
    bf16x8 af[4], bfr[4];
#pragma unroll
    for (int mi = 0; mi < 4; ++mi) af[mi]  = Ap[(wm * 64 + mi * 16 + rl) * 4 + kq];
#pragma unroll
    for (int ni = 0; ni < 4; ++ni) bfr[ni] = Bp[(wn * 64 + ni * 16 + rl) * 4 + kq];
#pragma unroll
    for (int mi = 0; mi < 4; ++mi)
#pragma unroll
      for (int ni = 0; ni < 4; ++ni)
        acc[mi][ni] = __builtin_amdgcn_mfma_f32_16x16x32_bf16(af[mi], bfr[ni], acc[mi][ni], 0, 0, 0);
  }

  // epilogue: C/D layout col = lane&15, row = (lane>>4)*4 + reg
#pragma unroll
  for (int mi = 0; mi < 4; ++mi){
#pragma unroll
    for (int ni = 0; ni < 4; ++ni){
      int col = n0 + wn * 64 + ni * 16 + rl;
      float bv = bias[col];
#pragma unroll
      for (int r = 0; r < 4; ++r){
        int row = m0 + wm * 64 + mi * 16 + kq * 4 + r;
        float v = acc[mi][ni][r] + bv;
        if (EPI == 0){
          v = fmaxf(v, 0.0f);
          ((unsigned short*)Cout)[(size_t)row * N + col] = f2bf(v);
        } else {
          v += resid[(size_t)row * N + col];
          ((float*)Cout)[(size_t)row * N + col] = v;
        }
      }
    }
  }
}

// ---------------- exact-f32 GEMM: xproj = x * win_w^T + win_b ----------------
// x:(16384,1024) f32, win_w:(256,1024) f32 -> xproj:(16384,256) f32
__global__ __launch_bounds__(256) void ssma_gemm3_f32(
    const float* __restrict__ A, const float* __restrict__ Bw,
    const float* __restrict__ bias, float* __restrict__ C)
{
  __shared__ float As[64][17];
  __shared__ float Bs[64][17];
  const int tid = threadIdx.x;
  const int tx = tid & 15, ty = tid >> 4;
  const int m0 = blockIdx.y * 64, n0 = blockIdx.x * 64;
  float acc[4][4];
#pragma unroll
  for (int i = 0; i < 4; ++i)
#pragma unroll
    for (int j = 0; j < 4; ++j) acc[i][j] = 0.f;

  for (int k0 = 0; k0 < DD; k0 += 16){
    __syncthreads();
#pragma unroll
    for (int i = 0; i < 4; ++i){
      int e = tid + 256 * i;          // 0..1023
      int r = e >> 4, c = e & 15;
      As[r][c] = A [(size_t)(m0 + r) * DD + k0 + c];
      Bs[r][c] = Bw[(size_t)(n0 + r) * DD + k0 + c];
    }
    __syncthreads();
#pragma unroll
    for (int kk = 0; kk < 16; ++kk){
      float a[4], b[4];
#pragma unroll
      for (int i = 0; i < 4; ++i) a[i] = As[ty * 4 + i][kk];
#pragma unroll
      for (int j = 0; j < 4; ++j) b[j] = Bs[tx * 4 + j][kk];
#pragma unroll
      for (int i = 0; i < 4; ++i)
#pragma unroll
        for (int j = 0; j < 4; ++j) acc[i][j] = fmaf(a[i], b[j], acc[i][j]);
    }
  }
#pragma unroll
  for (int i = 0; i < 4; ++i){
    int row = m0 + ty * 4 + i;
#pragma unroll
    for (int j = 0; j < 4; ++j){
      int col = n0 + tx * 4 + j;
      C[(size_t)row * MM + col] = acc[i][j] + bias[col];
    }
  }
}

// ---------------- sequential top-k gated scan ----------------
// 8 blocks (one per batch), 1024 threads: thread = (m = t>>2, q = t&3).
// Each thread holds wstate[m][64q..64q+63] in VGPRs. g lives in LDS.
// Gate: keep v iff #{j : v_j > v} <= top_k-1  (== v >= 32nd-largest, exact ties).
__global__ __launch_bounds__(1024) void ssma_scan(
    const float* __restrict__ xproj, const float* __restrict__ state,
    const float* __restrict__ wstate, const float* __restrict__ gamma_p,
    const int* __restrict__ topk_p, float* __restrict__ mem_out)
{
  __shared__ float g_lds[MM];
  __shared__ float su_lds[MM];
  const int tid = threadIdx.x;
  const int m = tid >> 2, q = tid & 3;
  const int b = blockIdx.x;
  const float gamma = *gamma_p;
  const float omg = 1.0f - gamma;
  const int rk = *topk_p - 1;

  float w[64];
  {
    const float* wr = wstate + m * MM + q * 64;
#pragma unroll
    for (int i = 0; i < 16; ++i){
      float4 v = *(const float4*)(wr + 4 * i);
      w[4*i+0] = v.x; w[4*i+1] = v.y; w[4*i+2] = v.z; w[4*i+3] = v.w;
    }
  }
  float st0 = state[b * MM + m];
  float mem = st0;
  if (q == 0) g_lds[m] = st0;
  const float* xp = xproj + (size_t)b * SS * MM;
  float xp_cur = xp[m];
  __syncthreads();

  for (int t = 0; t < SS; ++t){
    float xp_next = (t + 1 < SS) ? xp[(size_t)(t + 1) * MM + m] : 0.0f;

    // matvec: su_pre[m] = sum_j wstate[m][j] * g[j]
    float s = 0.f;
    const float4* gp = (const float4*)(g_lds + q * 64);
#pragma unroll
    for (int i = 0; i < 16; ++i){
      float4 gv = gp[i];
      s = fmaf(w[4*i+0], gv.x, s);
      s = fmaf(w[4*i+1], gv.y, s);
      s = fmaf(w[4*i+2], gv.z, s);
      s = fmaf(w[4*i+3], gv.w, s);
    }
    s += __shfl_xor(s, 1);
    s += __shfl_xor(s, 2);
    float su = fmaxf(s + xp_cur, 0.0f);
    if (q == 0) su_lds[m] = su;
    __syncthreads();                       // su ready; all matvec g-reads done

    // exact strict-rank: cnt = #{j in my 64-chunk : v_j > v_m}
    int cnt = 0;
    const float4* sp = (const float4*)(su_lds + q * 64);
#pragma unroll
    for (int i = 0; i < 16; ++i){
      float4 v = sp[i];
      cnt += (v.x > su); cnt += (v.y > su); cnt += (v.z > su); cnt += (v.w > su);
    }
    cnt += __shfl_xor(cnt, 1);
    cnt += __shfl_xor(cnt, 2);

    float g = (cnt <= rk) ? su : 0.0f;
    mem = fmaf(gamma, mem, omg * g);
    if (q == 0) g_lds[m] = g;
    xp_cur = xp_next;
    __syncthreads();                       // g visible for next matvec
  }
  if (q == 0) mem_out[b * MM + m] = mem;
}

extern "C" void kernel_launch(void* const* d_in, const int* in_sizes, int n_in,
                              void* d_out, int out_size, void* d_ws, size_t ws_size,
                              hipStream_t stream)
{
  const float* x      = (const float*)d_in[0];
  const float* state  = (const float*)d_in[1];
  // d_in[2]=U_w, d_in[3]=V_w are unused by the reference
  const float* w1     = (const float*)d_in[4];
  const float* b1     = (const float*)d_in[5];
  const float* w2     = (const float*)d_in[6];
  const float* b2     = (const float*)d_in[7];
  const float* win_w  = (const float*)d_in[8];
  const float* win_b  = (const float*)d_in[9];
  const float* wstate = (const float*)d_in[10];
  const float* gammap = (const float*)d_in[11];
  const int*   topkp  = (const int*)d_in[12];

  float* out  = (float*)d_out;                       // (8,2048,1024)
  float* memo = out + (size_t)BB * SS * DD;          // (8,256)

  char* ws = (char*)d_ws;
  unsigned short* xb   = (unsigned short*)(ws);                   // 32 MB
  unsigned short* w1b  = (unsigned short*)(ws + 33554432);        // 8 MB
  unsigned short* w2b  = (unsigned short*)(ws + 41943040);        // 8 MB
  unsigned short* hbuf = (unsigned short*)(ws + 50331648);        // 128 MB
  float*          xprj = (float*)(ws + 184549376);                // 16 MB

  ssma_pack_bf16<<<16384, 256, 0, stream>>>(x,  xb,  4194304);
  ssma_pack_bf16<<<4096,  256, 0, stream>>>(w1, w1b, 1048576);
  ssma_pack_bf16<<<4096,  256, 0, stream>>>(w2, w2b, 1048576);

  ssma_gemm3_f32<<<dim3(4, 256), 256, 0, stream>>>(x, win_w, win_b, xprj);

  // h = relu(x*w1^T + b1): M=16384, N=4096, K=1024
  ssma_gemm_bt<0><<<dim3(32, 128), 256, 0, stream>>>(xb, w1b, 1024, 4096, b1, nullptr, (void*)hbuf);
  // out = x + h*w2^T + b2: M=16384, N=1024, K=4096
  ssma_gemm_bt<1><<<dim3(8, 128), 256, 0, stream>>>(hbuf, w2b, 4096, 1024, b2, x, (void*)out);

  ssma_scan<<<BB, 1024, 0, stream>>>(xprj, state, wstate, gammap, topkp, memo);
}

// Round 3
// 5781.428 us; speedup vs baseline: 1.5056x; 1.5056x over previous
//
#include <hip/hip_runtime.h>
#include <stdint.h>

// Problem dims (fixed by setup_inputs)
#define BB 8
#define SS 2048
#define DD 1024
#define HH 4096
#define MM 256

typedef short bf16x8 __attribute__((ext_vector_type(8)));   // 8 bf16 in 4 VGPRs
typedef float f32x4 __attribute__((ext_vector_type(4)));

__device__ inline unsigned short f2bf(float f){
  unsigned u = __builtin_bit_cast(unsigned, f);
  return (unsigned short)((u + 0x7FFFu + ((u >> 16) & 1u)) >> 16);  // RNE
}

// ---------------- pack f32 -> bf16 (4 elems/thread) ----------------
__global__ void ssma_pack_bf16(const float* __restrict__ src,
                               unsigned short* __restrict__ dst, int n4){
  int i = blockIdx.x * blockDim.x + threadIdx.x;
  if (i < n4){
    float4 v = ((const float4*)src)[i];
    ushort4 o;
    o.x = f2bf(v.x); o.y = f2bf(v.y); o.z = f2bf(v.z); o.w = f2bf(v.w);
    ((ushort4*)dst)[i] = o;
  }
}

// ---------------- bf16 MFMA GEMM, C = A * B^T (+epilogue) ----------------
template<int EPI>
__global__ __launch_bounds__(256) void ssma_gemm_bt(
    const unsigned short* __restrict__ A, const unsigned short* __restrict__ Bw,
    int K, int N, const float* __restrict__ bias,
    const float* __restrict__ resid, void* __restrict__ Cout)
{
  __shared__ uint4 As4[512];   // 128x32 bf16 = 8KB
  __shared__ uint4 Bs4[512];
  unsigned short* As = (unsigned short*)As4;
  unsigned short* Bs = (unsigned short*)Bs4;

  const int tid  = threadIdx.x;
  const int lane = tid & 63;
  const int wv   = tid >> 6;
  const int wm   = wv >> 1, wn = wv & 1;      // 2x2 wave grid, 64x64 per wave
  const int m0   = blockIdx.y * 128;
  const int n0   = blockIdx.x * 128;
  const int kq   = lane >> 4;
  const int rl   = lane & 15;

  f32x4 acc[4][4];
#pragma unroll
  for (int a = 0; a < 4; ++a)
#pragma unroll
    for (int b = 0; b < 4; ++b) acc[a][b] = (f32x4){0.f, 0.f, 0.f, 0.f};

  for (int k0 = 0; k0 < K; k0 += 32){
    __syncthreads();
#pragma unroll
    for (int i = 0; i < 2; ++i){
      int c  = tid + 256 * i;
      int r  = c >> 2;
      int c8 = (c & 3) * 8;
      As4[c] = *(const uint4*)(A  + (size_t)(m0 + r) * K + k0 + c8);
      Bs4[c] = *(const uint4*)(Bw + (size_t)(n0 + r) * K + k0 + c8);
    }
    __syncthreads();

    const bf16x8* Ap = (const bf16x8*)As;
    const bf16x8* Bp = (const bf16x8*)Bs;
    bf16x8 af[4], bfr[4];
#pragma unroll
    for (int mi = 0; mi < 4; ++mi) af[mi]  = Ap[(wm * 64 + mi * 16 + rl) * 4 + kq];
#pragma unroll
    for (int ni = 0; ni < 4; ++ni) bfr[ni] = Bp[(wn * 64 + ni * 16 + rl) * 4 + kq];
#pragma unroll
    for (int mi = 0; mi < 4; ++mi)
#pragma unroll
      for (int ni = 0; ni < 4; ++ni)
        acc[mi][ni] = __builtin_amdgcn_mfma_f32_16x16x32_bf16(af[mi], bfr[ni], acc[mi][ni], 0, 0, 0);
  }

#pragma unroll
  for (int mi = 0; mi < 4; ++mi){
#pragma unroll
    for (int ni = 0; ni < 4; ++ni){
      int col = n0 + wn * 64 + ni * 16 + rl;
      float bv = bias[col];
#pragma unroll
      for (int r = 0; r < 4; ++r){
        int row = m0 + wm * 64 + mi * 16 + kq * 4 + r;
        float v = acc[mi][ni][r] + bv;
        if (EPI == 0){
          v = fmaxf(v, 0.0f);
          ((unsigned short*)Cout)[(size_t)row * N + col] = f2bf(v);
        } else {
          v += resid[(size_t)row * N + col];
          ((float*)Cout)[(size_t)row * N + col] = v;
        }
      }
    }
  }
}

// ---------------- exact-f32 GEMM: xproj = x * win_w^T + win_b ----------------
__global__ __launch_bounds__(256) void ssma_gemm3_f32(
    const float* __restrict__ A, const float* __restrict__ Bw,
    const float* __restrict__ bias, float* __restrict__ C)
{
  __shared__ float As[64][17];
  __shared__ float Bs[64][17];
  const int tid = threadIdx.x;
  const int tx = tid & 15, ty = tid >> 4;
  const int m0 = blockIdx.y * 64, n0 = blockIdx.x * 64;
  float acc[4][4];
#pragma unroll
  for (int i = 0; i < 4; ++i)
#pragma unroll
    for (int j = 0; j < 4; ++j) acc[i][j] = 0.f;

  for (int k0 = 0; k0 < DD; k0 += 16){
    __syncthreads();
#pragma unroll
    for (int i = 0; i < 4; ++i){
      int e = tid + 256 * i;
      int r = e >> 4, c = e & 15;
      As[r][c] = A [(size_t)(m0 + r) * DD + k0 + c];
      Bs[r][c] = Bw[(size_t)(n0 + r) * DD + k0 + c];
    }
    __syncthreads();
#pragma unroll
    for (int kk = 0; kk < 16; ++kk){
      float a[4], b[4];
#pragma unroll
      for (int i = 0; i < 4; ++i) a[i] = As[ty * 4 + i][kk];
#pragma unroll
      for (int j = 0; j < 4; ++j) b[j] = Bs[tx * 4 + j][kk];
#pragma unroll
      for (int i = 0; i < 4; ++i)
#pragma unroll
        for (int j = 0; j < 4; ++j) acc[i][j] = fmaf(a[i], b[j], acc[i][j]);
    }
  }
#pragma unroll
  for (int i = 0; i < 4; ++i){
    int row = m0 + ty * 4 + i;
#pragma unroll
    for (int j = 0; j < 4; ++j){
      int col = n0 + tx * 4 + j;
      C[(size_t)row * MM + col] = acc[i][j] + bias[col];
    }
  }
}

// ---------------- 256x256 f32 transpose (wstate -> wT) ----------------
__global__ __launch_bounds__(256) void ssma_transpose(
    const float* __restrict__ A, float* __restrict__ At)
{
  __shared__ float t[32][33];
  const int tx = threadIdx.x & 31, ty = threadIdx.x >> 5;  // 32x8
  const int x0 = blockIdx.x * 32, y0 = blockIdx.y * 32;
#pragma unroll
  for (int r = 0; r < 32; r += 8)
    t[ty + r][tx] = A[(size_t)(y0 + ty + r) * MM + x0 + tx];
  __syncthreads();
#pragma unroll
  for (int r = 0; r < 32; r += 8)
    At[(size_t)(x0 + ty + r) * MM + y0 + tx] = t[tx][ty + r];
}

// ---------------- sequential top-k gated scan, v2 ----------------
// 8 blocks (one per batch) x 512 threads (8 waves).
// Per step:
//  - waves 0..3 (tid<256, m=tid): sparse matvec su[m] = relu(xp + sum_s wT[j_s][m]*g_s)
//    over the compacted nonzero list of g (<=32 entries typ.), gathered from L2.
//  - all 8 waves: exact strict-rank of su among COMPACTED POSITIVES only
//    (zeros can't outrank a positive; su==0 rows get g=0 anyway).
//    wave wv covers rows m2 = 32*wv + (lane&31); lane-half h=lane>>5 counts one
//    half of the list (uniform trip count), combined via shfl_xor(cnt,32).
//  - deterministic ballot+prefix compaction (no atomics) for both lists.
// All LDS reads are wave-uniform broadcasts or 2-way -> no bank conflicts.
__global__ __launch_bounds__(512) void ssma_scan2(
    const float* __restrict__ xproj, const float* __restrict__ state,
    const float* __restrict__ wT, const float* __restrict__ gamma_p,
    const int* __restrict__ topk_p, float* __restrict__ mem_out)
{
  __shared__ __align__(16) float su_all[MM];
  __shared__ __align__(16) float su_pos[MM + 32];
  __shared__ __align__(16) float val_list[MM + 8];
  __shared__ __align__(16) int   idx_list[MM + 8];
  __shared__ unsigned long long  umask[4];
  __shared__ unsigned int        kmask[8];

  const int tid  = threadIdx.x;
  const int wv   = tid >> 6;
  const int lane = tid & 63;
  const int b    = blockIdx.x;
  const float gamma = *gamma_p;
  const float omg   = 1.0f - gamma;
  const int   rk    = *topk_p - 1;

  const int m  = tid;             // matvec row (valid for wv<4)
  const int hl = lane & 31;
  const int h  = lane >> 5;       // rank half
  const int m2 = wv * 32 + hl;    // rank row (all 8 waves)

  const float* xp  = xproj + (size_t)b * SS * MM;
  const float* wTm = wT + m;      // never dereferenced for wv>=4

  float mem = state[b * MM + m2]; // lanes h=0/h=1 read same addr (broadcast)

  // ---- initial sparse list from the state row (general: state may be nonzero) ----
  int nk_ch;
  float st0 = 0.0f;
  if (wv < 4){
    st0 = state[b * MM + m];
    unsigned long long pmi = __ballot(st0 != 0.0f);
    if (lane == 0) umask[wv] = pmi;
  }
  __syncthreads();
  {
    unsigned long long u0 = umask[0], u1 = umask[1], u2 = umask[2], u3 = umask[3];
    int nk = __popcll(u0) + __popcll(u1) + __popcll(u2) + __popcll(u3);
    if (wv < 4 && st0 != 0.0f){
      int before = (wv > 0 ? __popcll(u0) : 0) + (wv > 1 ? __popcll(u1) : 0)
                 + (wv > 2 ? __popcll(u2) : 0);
      unsigned long long pmw = (wv == 0 ? u0 : wv == 1 ? u1 : wv == 2 ? u2 : u3);
      int pos = before + __popcll(pmw & ((1ull << lane) - 1ull));
      idx_list[pos] = m << 8;     // j * 256 (float offset of wT row)
      val_list[pos] = st0;
    }
    if (tid < 8){ idx_list[nk + tid] = 0; val_list[nk + tid] = 0.0f; }
    nk_ch = (nk + 7) >> 3;
  }
  __syncthreads();

  float xp_cur = (wv < 4) ? xp[m] : 0.0f;

  for (int t = 0; t < SS; ++t){
    float su = 0.0f;
    unsigned long long pm = 0;
    float xp_next = 0.0f;
    if (wv < 4){
      int tn = (t + 1 < SS) ? t + 1 : SS - 1;
      xp_next = xp[(size_t)tn * MM + m];
      float s0=0.f,s1=0.f,s2=0.f,s3=0.f,s4=0.f,s5=0.f,s6=0.f,s7=0.f;
      const int4*   ipb = (const int4*)idx_list;
      const float4* vpb = (const float4*)val_list;
      for (int c = 0; c < nk_ch; ++c){
        int4   ia = ipb[2*c], ib = ipb[2*c+1];
        float4 va = vpb[2*c], vb = vpb[2*c+1];
        float w0 = wTm[ia.x], w1 = wTm[ia.y], w2 = wTm[ia.z], w3 = wTm[ia.w];
        float w4 = wTm[ib.x], w5 = wTm[ib.y], w6 = wTm[ib.z], w7 = wTm[ib.w];
        s0 = fmaf(w0, va.x, s0); s1 = fmaf(w1, va.y, s1);
        s2 = fmaf(w2, va.z, s2); s3 = fmaf(w3, va.w, s3);
        s4 = fmaf(w4, vb.x, s4); s5 = fmaf(w5, vb.y, s5);
        s6 = fmaf(w6, vb.z, s6); s7 = fmaf(w7, vb.w, s7);
      }
      float s = ((s0 + s1) + (s2 + s3)) + ((s4 + s5) + (s6 + s7));
      su = fmaxf(s + xp_cur, 0.0f);
      su_all[m] = su;
      pm = __ballot(su > 0.0f);
      if (lane == 0) umask[wv] = pm;
    }
    __syncthreads();   // B1: umask + su_all ready

    int P;
    {
      unsigned long long u0 = umask[0], u1 = umask[1], u2 = umask[2], u3 = umask[3];
      P = __popcll(u0) + __popcll(u1) + __popcll(u2) + __popcll(u3);
      if (wv < 4 && su > 0.0f){
        int before = (wv > 0 ? __popcll(u0) : 0) + (wv > 1 ? __popcll(u1) : 0)
                   + (wv > 2 ? __popcll(u2) : 0);
        int pos = before + __popcll(pm & ((1ull << lane) - 1ull));
        su_pos[pos] = su;
      }
    }
    if (tid < 32) su_pos[P + tid] = 0.0f;
    __syncthreads();   // B2: su_pos ready

    // rank among positives; half per lane-group, uniform trip count
    float su2 = su_all[m2];
    int CH16 = ((P + 31) >> 5) << 1;      // even count of 16-float chunks
    int half = CH16 >> 1;
    int base4 = h * half * 4;             // float4 index base
    int cnt = 0;
    const float4* spp = (const float4*)su_pos;
    for (int c = 0; c < half; ++c){
      float4 a = spp[base4 + 4*c + 0];
      float4 q = spp[base4 + 4*c + 1];
      float4 r = spp[base4 + 4*c + 2];
      float4 d = spp[base4 + 4*c + 3];
      cnt += (a.x > su2) + (a.y > su2) + (a.z > su2) + (a.w > su2)
           + (q.x > su2) + (q.y > su2) + (q.z > su2) + (q.w > su2)
           + (r.x > su2) + (r.y > su2) + (r.z > su2) + (r.w > su2)
           + (d.x > su2) + (d.y > su2) + (d.z > su2) + (d.w > su2);
    }
    cnt += __shfl_xor(cnt, 32);
    float g = (su2 > 0.0f && cnt <= rk) ? su2 : 0.0f;
    if (h == 0) mem = fmaf(gamma, mem, omg * g);
    unsigned int km = (unsigned int)(__ballot(h == 0 && g > 0.0f) & 0xffffffffull);
    if (lane == 0) kmask[wv] = km;
    __syncthreads();   // B3: kmask ready

    {
      int nk = 0, before2 = 0;
#pragma unroll
      for (int wi = 0; wi < 8; ++wi){
        int pc = __popc(kmask[wi]);
        nk += pc;
        if (wi < wv) before2 += pc;
      }
      if (h == 0 && g > 0.0f){
        int pos2 = before2 + __popc(km & ((1u << hl) - 1u));
        idx_list[pos2] = m2 << 8;
        val_list[pos2] = g;
      }
      if (tid < 8){ idx_list[nk + tid] = 0; val_list[nk + tid] = 0.0f; }
      nk_ch = (nk + 7) >> 3;
    }
    xp_cur = xp_next;
    __syncthreads();   // B4: lists ready for next step's matvec
  }
  if (h == 0) mem_out[b * MM + m2] = mem;
}

extern "C" void kernel_launch(void* const* d_in, const int* in_sizes, int n_in,
                              void* d_out, int out_size, void* d_ws, size_t ws_size,
                              hipStream_t stream)
{
  const float* x      = (const float*)d_in[0];
  const float* state  = (const float*)d_in[1];
  // d_in[2]=U_w, d_in[3]=V_w unused by the reference
  const float* w1     = (const float*)d_in[4];
  const float* b1     = (const float*)d_in[5];
  const float* w2     = (const float*)d_in[6];
  const float* b2     = (const float*)d_in[7];
  const float* win_w  = (const float*)d_in[8];
  const float* win_b  = (const float*)d_in[9];
  const float* wstate = (const float*)d_in[10];
  const float* gammap = (const float*)d_in[11];
  const int*   topkp  = (const int*)d_in[12];

  float* out  = (float*)d_out;                       // (8,2048,1024)
  float* memo = out + (size_t)BB * SS * DD;          // (8,256)

  char* ws = (char*)d_ws;
  unsigned short* xb   = (unsigned short*)(ws);                   // 32 MB
  unsigned short* w1b  = (unsigned short*)(ws + 33554432);        // 8 MB (reused for wT after gemm1)
  unsigned short* w2b  = (unsigned short*)(ws + 41943040);        // 8 MB
  unsigned short* hbuf = (unsigned short*)(ws + 50331648);        // 128 MB
  float*          xprj = (float*)(ws + 184549376);                // 16 MB
  float*          wT   = (float*)(ws + 33554432);                 // 256 KB, after gemm1

  ssma_pack_bf16<<<16384, 256, 0, stream>>>(x,  xb,  4194304);
  ssma_pack_bf16<<<4096,  256, 0, stream>>>(w1, w1b, 1048576);
  ssma_pack_bf16<<<4096,  256, 0, stream>>>(w2, w2b, 1048576);

  ssma_gemm3_f32<<<dim3(4, 256), 256, 0, stream>>>(x, win_w, win_b, xprj);

  // h = relu(x*w1^T + b1): M=16384, N=4096, K=1024
  ssma_gemm_bt<0><<<dim3(32, 128), 256, 0, stream>>>(xb, w1b, 1024, 4096, b1, nullptr, (void*)hbuf);

  // wT = wstate^T (w1b region is dead after gemm1)
  ssma_transpose<<<dim3(8, 8), 256, 0, stream>>>(wstate, wT);

  // out = x + h*w2^T + b2: M=16384, N=1024, K=4096
  ssma_gemm_bt<1><<<dim3(8, 128), 256, 0, stream>>>(hbuf, w2b, 4096, 1024, b2, x, (void*)out);

  ssma_scan2<<<BB, 512, 0, stream>>>(xprj, state, wT, gammap, topkp, memo);
}